// Round 1
// baseline (1070.380 us; speedup 1.0000x reference)
//
#include <hip/hip_runtime.h>

#define NB 8
#define NN 2048
#define MM 2048
#define DD 64
#define NCHK 16
#define TS 128
#define L2E 1.4426950408889634f
#define LN2 0.6931471805599453f

typedef _Float16 half_t;
typedef __attribute__((ext_vector_type(8))) _Float16 f16x8;
typedef __attribute__((ext_vector_type(4))) float f32x4;

// ---------------------------------------------------------------------------
// Static device scratch. C is never materialized: tiles are recomputed by
// MFMA inside the softmin pass (fragments are L2-resident, 4.2 MB total).
// h-vectors, a/b logs, and softmin partials live in the log2 domain
// (scaled by log2(e)) so phase B uses native v_exp_f32 directly.
// ---------------------------------------------------------------------------
__device__ half_t g_xh[NB * NN * DD];           // fp16 copies for MFMA
__device__ half_t g_yh[NB * MM * DD];
// potential banks: [0]/[1] = carry double-buffer, [2] = final (natural units)
__device__ float g_fab[3][NB * NN], g_gba[3][NB * NN];
__device__ float g_faa[3][NB * NN], g_gbb[3][NB * NN];
__device__ float g_alog[NB * NN], g_blog[NB * NN];   // log2(w)  (log2 domain)
__device__ float g_xn[NB * NN], g_yn[NB * NN];       // 0.5*||row||^2 (natural)
__device__ float g_h0[NB * MM], g_h1[NB * NN], g_h2[NB * NN], g_h3[NB * MM];
// chunked softmin partials (m,s) in log2 domain: [b][chunk][row]
__device__ float2 g_pfab[NB * NCHK * NN];
__device__ float2 g_pgba[NB * NCHK * NN];
__device__ float2 g_pfaa[NB * NCHK * NN];
__device__ float2 g_pgbb[NB * NCHK * NN];

// ---------------------------------------------------------------------------
// prep: a_log/b_log = log2(w), xn/yn = 0.5*||row||^2, and fp16 copies of x,y.
// ---------------------------------------------------------------------------
__global__ __launch_bounds__(256) void prep_kernel(
    const float* __restrict__ x, const float* __restrict__ y,
    const float* __restrict__ w1, const float* __restrict__ w2)
{
  int gid = blockIdx.x * 256 + threadIdx.x;
  if (gid < NB * NN) {
    g_alog[gid] = log2f(w1[gid]);
    g_blog[gid] = log2f(w2[gid]);
  }
  int lane = threadIdx.x & 63;
  int row = blockIdx.x * 4 + (threadIdx.x >> 6);   // grid 4096 -> rows 0..16383
  float xv = x[(size_t)row * DD + lane];
  float yv = y[(size_t)row * DD + lane];
  g_xh[(size_t)row * DD + lane] = (half_t)xv;
  g_yh[(size_t)row * DD + lane] = (half_t)yv;
  float sx = xv * xv;
  float sy = yv * yv;
#pragma unroll
  for (int off = 32; off > 0; off >>= 1) {
    sx += __shfl_down(sx, off);
    sy += __shfl_down(sy, off);
  }
  if (lane == 0) {
    g_xn[row] = 0.5f * sx;
    g_yn[row] = 0.5f * sy;
  }
}

// ---------------------------------------------------------------------------
// h-vector prep — used ONCE for the init step (gs = 0); subsequent h's are
// written by merge4. h in log2 domain (g_blog/g_alog already log2-scaled).
// ---------------------------------------------------------------------------
__global__ __launch_bounds__(256) void hprep_kernel(
    const float* __restrict__ fab_in, const float* __restrict__ gba_in,
    const float* __restrict__ faa_in, const float* __restrict__ gbb_in,
    float gs2)
{
  int i = blockIdx.x * 256 + threadIdx.x;   // grid 64 -> 16384
  g_h0[i] = fmaf(gs2, gba_in[i], g_blog[i]);
  g_h1[i] = fmaf(gs2, fab_in[i], g_alog[i]);
  g_h2[i] = fmaf(gs2, faa_in[i], g_alog[i]);
  g_h3[i] = fmaf(gs2, gbb_in[i], g_blog[i]);
}

// ---------------------------------------------------------------------------
// Fused cost-recompute + tile-partial softmin.
// 128x128 tile per block (4 waves; wave w = rows 32w..32w+31 as 2 row-groups
// x 8 col-groups). MFMA fragment code copied verbatim from the verified
// cost_mfma (A[m=lane&15][k=quad*8+j]; D col=16c+(lane&15), row=quad*4+reg).
// base_ij = min(dot - xn - yn, 0) * (log2e/eps)  (= -C_ij/eps in log2 units)
// then two-phase (max, sum-of-exp2) reduction identical in structure to the
// verified tile_pass.
// ---------------------------------------------------------------------------
struct FusedArgs {
  const half_t* Af;     // fragment rows (x or y)
  const half_t* Bf;     // fragment cols
  const float* nrow;    // xn or yn for rows
  const float* ncol;    // for cols
  const float* hrow;    // h over cols (added along row direction), log2 dom.
  const float* hcol;    // h over rows
  float2* prow;         // [b][chunk][row]
  float2* pcol;
  int sym;              // 1 => triangular tile enumeration (136 tiles)
};

__global__ __launch_bounds__(256) void tile_fused(
    FusedArgs T0, FusedArgs T1, FusedArgs T2, float keps)   // keps = log2e/eps
{
  FusedArgs A = (blockIdx.z == 0) ? T0 : (blockIdx.z == 1) ? T1 : T2;
  int I, J;
  if (A.sym) {
    if (blockIdx.x >= 136) return;
    int rem = blockIdx.x, ii = 0;
    while (rem >= NCHK - ii) { rem -= NCHK - ii; ++ii; }   // uniform, <=16 iters
    I = ii; J = ii + rem;                                  // I <= J
  } else {
    I = blockIdx.x >> 4;
    J = blockIdx.x & 15;
  }
  const int b = blockIdx.y;
  const int t = threadIdx.x;
  const int w = t >> 6, lane = t & 63;
  const int m = lane & 15, quad = lane >> 4;
  const int i0 = I * TS, j0 = J * TS;

  // ---- MFMA: dot products for this 128x128 tile ----
  const half_t* Abase = A.Af + ((size_t)b * NN + i0 + 32 * w + m) * DD + quad * 8;
  const half_t* Bbase = A.Bf + ((size_t)b * MM + j0 + m) * DD + quad * 8;

  f32x4 acc[2][8];
#pragma unroll
  for (int g = 0; g < 2; ++g)
#pragma unroll
    for (int c = 0; c < 8; ++c) acc[g][c] = (f32x4){0.f, 0.f, 0.f, 0.f};

#pragma unroll
  for (int s = 0; s < 2; ++s) {
    f16x8 a0 = *(const f16x8*)(Abase + s * 32);
    f16x8 a1 = *(const f16x8*)(Abase + (size_t)16 * DD + s * 32);
#pragma unroll
    for (int c = 0; c < 8; ++c) {
      f16x8 bf = *(const f16x8*)(Bbase + (size_t)(16 * c) * DD + s * 32);
      acc[0][c] = __builtin_amdgcn_mfma_f32_16x16x32_f16(a0, bf, acc[0][c], 0, 0, 0);
      acc[1][c] = __builtin_amdgcn_mfma_f32_16x16x32_f16(a1, bf, acc[1][c], 0, 0, 0);
    }
  }

  // ---- per-thread row/col scalars ----
  float4 xr[2], hq[2];
#pragma unroll
  for (int g = 0; g < 2; ++g) {
    size_t ro = (size_t)b * NN + i0 + 32 * w + 16 * g + 4 * quad;
    xr[g] = *(const float4*)(A.nrow + ro);
    hq[g] = *(const float4*)(A.hcol + ro);
  }
  float ynk[8], hr[8];
#pragma unroll
  for (int c = 0; c < 8; ++c) {
    size_t co = (size_t)b * MM + j0 + 16 * c + m;
    ynk[c] = -A.ncol[co] * keps;
    hr[c] = A.hrow[co];
  }
  float xnk[2][4], hcv[2][4];
#pragma unroll
  for (int g = 0; g < 2; ++g) {
    xnk[g][0] = -xr[g].x * keps; xnk[g][1] = -xr[g].y * keps;
    xnk[g][2] = -xr[g].z * keps; xnk[g][3] = -xr[g].w * keps;
    hcv[g][0] = hq[g].x; hcv[g][1] = hq[g].y;
    hcv[g][2] = hq[g].z; hcv[g][3] = hq[g].w;
  }

  // ---- phase A: base conversion (in place) + row/col maxes ----
  float rm[2][4], cm[8];
#pragma unroll
  for (int g = 0; g < 2; ++g)
#pragma unroll
    for (int r = 0; r < 4; ++r) rm[g][r] = -3.0e38f;
#pragma unroll
  for (int c = 0; c < 8; ++c) cm[c] = -3.0e38f;

#pragma unroll
  for (int g = 0; g < 2; ++g)
#pragma unroll
    for (int c = 0; c < 8; ++c) {
      f32x4 v = acc[g][c];
#pragma unroll
      for (int r = 0; r < 4; ++r) {
        float bse = fminf(fmaf(v[r], keps, xnk[g][r]) + ynk[c], 0.f);
        v[r] = bse;
        rm[g][r] = fmaxf(rm[g][r], bse + hr[c]);
        cm[c] = fmaxf(cm[c], bse + hcv[g][r]);
      }
      acc[g][c] = v;
    }

  __shared__ float redR[TS][17], redC[TS][17];   // odd stride: reduce reads CF
  __shared__ float rowM[TS], colM[TS];

#pragma unroll
  for (int g = 0; g < 2; ++g)
#pragma unroll
    for (int r = 0; r < 4; ++r)
      redR[32 * w + 16 * g + 4 * quad + r][m] = rm[g][r];
#pragma unroll
  for (int c = 0; c < 8; ++c)
    redC[16 * c + m][4 * w + quad] = cm[c];
  __syncthreads();
  if (t < TS) {
    float mx = redR[t][0];
#pragma unroll
    for (int k = 1; k < 16; ++k) mx = fmaxf(mx, redR[t][k]);
    rowM[t] = mx;
  } else {
    int tt = t - TS;
    float mx = redC[tt][0];
#pragma unroll
    for (int k = 1; k < 16; ++k) mx = fmaxf(mx, redC[tt][k]);
    colM[tt] = mx;
  }
  __syncthreads();

  float rmv[2][4], cmv[8];
#pragma unroll
  for (int g = 0; g < 2; ++g) {
    float4 q = *(const float4*)&rowM[32 * w + 16 * g + 4 * quad];
    rmv[g][0] = q.x; rmv[g][1] = q.y; rmv[g][2] = q.z; rmv[g][3] = q.w;
  }
#pragma unroll
  for (int c = 0; c < 8; ++c) cmv[c] = colM[16 * c + m];

  // ---- phase B: sums of exp2 (base values still in registers) ----
  float rs[2][4], cs[8];
#pragma unroll
  for (int g = 0; g < 2; ++g)
#pragma unroll
    for (int r = 0; r < 4; ++r) rs[g][r] = 0.f;
#pragma unroll
  for (int c = 0; c < 8; ++c) cs[c] = 0.f;

#pragma unroll
  for (int g = 0; g < 2; ++g)
#pragma unroll
    for (int c = 0; c < 8; ++c) {
      f32x4 v = acc[g][c];
#pragma unroll
      for (int r = 0; r < 4; ++r) {
        rs[g][r] += __builtin_amdgcn_exp2f(v[r] + hr[c] - rmv[g][r]);
        cs[c] += __builtin_amdgcn_exp2f(v[r] + hcv[g][r] - cmv[c]);
      }
    }

#pragma unroll
  for (int g = 0; g < 2; ++g)
#pragma unroll
    for (int r = 0; r < 4; ++r)
      redR[32 * w + 16 * g + 4 * quad + r][m] = rs[g][r];
#pragma unroll
  for (int c = 0; c < 8; ++c)
    redC[16 * c + m][4 * w + quad] = cs[c];
  __syncthreads();
  if (t < TS) {
    float s = 0.f;
#pragma unroll
    for (int k = 0; k < 16; ++k) s += redR[t][k];
    A.prow[((size_t)b * NCHK + J) * NN + i0 + t] = make_float2(rowM[t], s);
  } else {
    int tt = t - TS;
    if (!(A.sym && I == J)) {   // diagonal col-dir duplicates row-dir: skip
      float s = 0.f;
#pragma unroll
      for (int k = 0; k < 16; ++k) s += redC[tt][k];
      A.pcol[((size_t)b * NCHK + I) * NN + j0 + tt] = make_float2(colM[tt], s);
    }
  }
}

// ---------------------------------------------------------------------------
// merge 16 chunk-partials per row -> softmin + Jacobi update + next-h write.
// Partials in log2 domain: ft = -eps*ln2*(M + log2(S)). f banks in natural
// units; hout written in log2 domain.
// ---------------------------------------------------------------------------
struct MergeArgs {
  const float2* part;
  const float* fold;
  float* fout;
  const float* hbase;   // alog or blog (log2 domain)
  float* hout;          // h vector consumed by the next tile_fused
};

__global__ __launch_bounds__(256) void merge4(
    MergeArgs M0, MergeArgs M1, MergeArgs M2, MergeArgs M3,
    float eps, float alpha, float beta, float nextgs)
{
  MergeArgs A = (blockIdx.z == 0) ? M0 : (blockIdx.z == 1) ? M1
              : (blockIdx.z == 2) ? M2 : M3;
  const int b = blockIdx.y;
  const int i = blockIdx.x * 256 + threadIdx.x;   // grid.x = NN/256
  float2 p[NCHK];
#pragma unroll
  for (int k = 0; k < NCHK; ++k)
    p[k] = A.part[((size_t)b * NCHK + k) * NN + i];
  float M = p[0].x;
#pragma unroll
  for (int k = 1; k < NCHK; ++k) M = fmaxf(M, p[k].x);
  float S = 0.f;
#pragma unroll
  for (int k = 0; k < NCHK; ++k) S += p[k].y * __builtin_amdgcn_exp2f(p[k].x - M);
  float ft = (-LN2 * eps) * (M + __log2f(S));
  int idx = b * NN + i;
  float fnew = alpha * A.fold[idx] + beta * ft;
  A.fout[idx] = fnew;
  A.hout[idx] = fmaf(nextgs * L2E, fnew, A.hbase[idx]);
}

// ---------------------------------------------------------------------------
// loss = mean_b [ sum_i w1*(fabf - faaf) + sum_j w2*(gbaf - gbbf) ]
// ---------------------------------------------------------------------------
__global__ __launch_bounds__(256) void loss_kernel(
    const float* __restrict__ w1, const float* __restrict__ w2,
    float* __restrict__ out)
{
  __shared__ float red[256];
  float acc = 0.f;
  for (int idx = threadIdx.x; idx < NB * NN; idx += 256) {
    acc += w1[idx] * (g_fab[2][idx] - g_faa[2][idx])
         + w2[idx] * (g_gba[2][idx] - g_gbb[2][idx]);
  }
  red[threadIdx.x] = acc;
  __syncthreads();
  for (int s = 128; s > 0; s >>= 1) {
    if (threadIdx.x < s) red[threadIdx.x] += red[threadIdx.x + s];
    __syncthreads();
  }
  if (threadIdx.x == 0) out[0] = red[0] * (1.0f / NB);
}

// ---------------------------------------------------------------------------
extern "C" void kernel_launch(void* const* d_in, const int* in_sizes, int n_in,
                              void* d_out, int out_size, void* d_ws, size_t ws_size,
                              hipStream_t stream)
{
  const float* x = (const float*)d_in[0];
  const float* y = (const float*)d_in[1];
  const float* w1 = (const float*)d_in[2];
  const float* w2 = (const float*)d_in[3];
  float* out = (float*)d_out;

  half_t *xh, *yh;
  float *xn, *yn;
  float *h0, *h1, *h2, *h3, *fabp, *gbap, *faap, *gbbp, *alog, *blog;
  float2 *pfab, *pgba, *pfaa, *pgbb;
  hipGetSymbolAddress((void**)&xh, HIP_SYMBOL(g_xh));
  hipGetSymbolAddress((void**)&yh, HIP_SYMBOL(g_yh));
  hipGetSymbolAddress((void**)&xn, HIP_SYMBOL(g_xn));
  hipGetSymbolAddress((void**)&yn, HIP_SYMBOL(g_yn));
  hipGetSymbolAddress((void**)&h0, HIP_SYMBOL(g_h0));
  hipGetSymbolAddress((void**)&h1, HIP_SYMBOL(g_h1));
  hipGetSymbolAddress((void**)&h2, HIP_SYMBOL(g_h2));
  hipGetSymbolAddress((void**)&h3, HIP_SYMBOL(g_h3));
  hipGetSymbolAddress((void**)&fabp, HIP_SYMBOL(g_fab));
  hipGetSymbolAddress((void**)&gbap, HIP_SYMBOL(g_gba));
  hipGetSymbolAddress((void**)&faap, HIP_SYMBOL(g_faa));
  hipGetSymbolAddress((void**)&gbbp, HIP_SYMBOL(g_gbb));
  hipGetSymbolAddress((void**)&alog, HIP_SYMBOL(g_alog));
  hipGetSymbolAddress((void**)&blog, HIP_SYMBOL(g_blog));
  hipGetSymbolAddress((void**)&pfab, HIP_SYMBOL(g_pfab));
  hipGetSymbolAddress((void**)&pgba, HIP_SYMBOL(g_pgba));
  hipGetSymbolAddress((void**)&pfaa, HIP_SYMBOL(g_pfaa));
  hipGetSymbolAddress((void**)&pgbb, HIP_SYMBOL(g_pgbb));

  auto fab = [&](int s) { return fabp + (size_t)s * NB * NN; };
  auto gba = [&](int s) { return gbap + (size_t)s * NB * NN; };
  auto faa = [&](int s) { return faap + (size_t)s * NB * NN; };
  auto gbb = [&](int s) { return gbbp + (size_t)s * NB * NN; };

  // eps schedule (matches the Python double loop, then cast to fp32)
  float eps_list[32];
  int ne = 0;
  {
    double v = 64.0 * 64.0;
    double tgt = 0.05 * 0.05;
    while (v > tgt) { eps_list[ne++] = (float)v; v *= 0.25; }
    eps_list[ne++] = (float)tgt;   // ne == 12
  }

  prep_kernel<<<4096, 256, 0, stream>>>(x, y, w1, w2);

  dim3 tg(256, NB, 3);          // z: 0=xy(256 tiles), 1/2=xx/yy(tri 136)
  dim3 mg(NN / 256, NB, 4);     // z: potential

  // one iteration: tile_fused (h already in place) + merge4 (writes next h)
  auto launch_iter = [&](float eps, float alpha, float beta, float nextgs,
                         int in, int outsel) {
    float keps = L2E / eps;
    FusedArgs T0 = {xh, yh, xn, yn, h0, h1, pfab, pgba, 0};
    FusedArgs T1 = {xh, xh, xn, xn, h2, h2, pfaa, pfaa, 1};
    FusedArgs T2 = {yh, yh, yn, yn, h3, h3, pgbb, pgbb, 1};
    tile_fused<<<tg, 256, 0, stream>>>(T0, T1, T2, keps);
    MergeArgs M0 = {pfab, fab(in), fab(outsel), alog, h1};
    MergeArgs M1 = {pgba, gba(in), gba(outsel), blog, h0};
    MergeArgs M2 = {pfaa, faa(in), faa(outsel), alog, h2};
    MergeArgs M3 = {pgbb, gbb(in), gbb(outsel), blog, h3};
    merge4<<<mg, 256, 0, stream>>>(M0, M1, M2, M3, eps, alpha, beta, nextgs);
  };

  // init at eps0: h = base log2-weights (gs=0), alpha=0 -> no carry read;
  // its merge writes h for scan step k=0.
  hprep_kernel<<<64, 256, 0, stream>>>(fab(0), gba(0), faa(0), gbb(0), 0.f);
  launch_iter(eps_list[0], 0.f, 1.f, 1.0f / eps_list[0], 0, 0);

  // scan over the full eps list with 0.5-averaging (Jacobi, banks 0/1);
  // each merge writes h for the NEXT step (k+1, or the final extrapolation).
  int cur = 0;
  for (int k = 0; k < ne; ++k) {
    int nxt = 1 - cur;
    float nextgs = 1.0f / ((k < ne - 1) ? eps_list[k + 1] : eps_list[ne - 1]);
    launch_iter(eps_list[k], 0.5f, 0.5f, nextgs, cur, nxt);
    cur = nxt;
  }

  // final extrapolation at eps = blur^p (no averaging) -> bank 2
  launch_iter(eps_list[ne - 1], 0.f, 1.f, 0.f, cur, 2);

  loss_kernel<<<1, 256, 0, stream>>>(w1, w2, out);
}

// Round 2
// 762.617 us; speedup vs baseline: 1.4036x; 1.4036x over previous
//
#include <hip/hip_runtime.h>

#define NB 8
#define NN 2048
#define MM 2048
#define DD 64
#define NCHK 16
#define TS 128
#define L2E 1.4426950408889634f
#define LN2 0.6931471805599453f

typedef _Float16 half_t;
typedef __attribute__((ext_vector_type(8))) _Float16 f16x8;
typedef __attribute__((ext_vector_type(4))) float f32x4;

// ---------------------------------------------------------------------------
// Static device scratch. C is never materialized: tiles are recomputed by
// MFMA inside the softmin pass from LDS-staged fp16 fragments.
// h-vectors, a/b logs, and softmin partials live in the log2 domain.
// ---------------------------------------------------------------------------
__device__ half_t g_xh[NB * NN * DD];           // fp16 copies for MFMA
__device__ half_t g_yh[NB * MM * DD];
// potential banks: [0]/[1] = carry double-buffer, [2] = final (natural units)
__device__ float g_fab[3][NB * NN], g_gba[3][NB * NN];
__device__ float g_faa[3][NB * NN], g_gbb[3][NB * NN];
__device__ float g_alog[NB * NN], g_blog[NB * NN];   // log2(w)
__device__ float g_xn[NB * NN], g_yn[NB * NN];       // 0.5*||row||^2 (natural)
__device__ float g_h0[NB * MM], g_h1[NB * NN], g_h2[NB * NN], g_h3[NB * MM];
// chunked softmin partials (m,s) in log2 domain: [b][chunk][row]
__device__ float2 g_pfab[NB * NCHK * NN];
__device__ float2 g_pgba[NB * NCHK * NN];
__device__ float2 g_pfaa[NB * NCHK * NN];
__device__ float2 g_pgbb[NB * NCHK * NN];

// ---------------------------------------------------------------------------
// prep: a_log/b_log = log2(w), xn/yn = 0.5*||row||^2, and fp16 copies of x,y.
// ---------------------------------------------------------------------------
__global__ __launch_bounds__(256) void prep_kernel(
    const float* __restrict__ x, const float* __restrict__ y,
    const float* __restrict__ w1, const float* __restrict__ w2)
{
  int gid = blockIdx.x * 256 + threadIdx.x;
  if (gid < NB * NN) {
    g_alog[gid] = log2f(w1[gid]);
    g_blog[gid] = log2f(w2[gid]);
  }
  int lane = threadIdx.x & 63;
  int row = blockIdx.x * 4 + (threadIdx.x >> 6);   // grid 4096 -> rows 0..16383
  float xv = x[(size_t)row * DD + lane];
  float yv = y[(size_t)row * DD + lane];
  g_xh[(size_t)row * DD + lane] = (half_t)xv;
  g_yh[(size_t)row * DD + lane] = (half_t)yv;
  float sx = xv * xv;
  float sy = yv * yv;
#pragma unroll
  for (int off = 32; off > 0; off >>= 1) {
    sx += __shfl_down(sx, off);
    sy += __shfl_down(sy, off);
  }
  if (lane == 0) {
    g_xn[row] = 0.5f * sx;
    g_yn[row] = 0.5f * sy;
  }
}

// ---------------------------------------------------------------------------
// h-vector prep — used ONCE for the init step (gs = 0); subsequent h's are
// written by merge4. h in log2 domain.
// ---------------------------------------------------------------------------
__global__ __launch_bounds__(256) void hprep_kernel(
    const float* __restrict__ fab_in, const float* __restrict__ gba_in,
    const float* __restrict__ faa_in, const float* __restrict__ gbb_in,
    float gs2)
{
  int i = blockIdx.x * 256 + threadIdx.x;   // grid 64 -> 16384
  g_h0[i] = fmaf(gs2, gba_in[i], g_blog[i]);
  g_h1[i] = fmaf(gs2, fab_in[i], g_alog[i]);
  g_h2[i] = fmaf(gs2, faa_in[i], g_alog[i]);
  g_h3[i] = fmaf(gs2, gbb_in[i], g_blog[i]);
}

// ---------------------------------------------------------------------------
// Fused cost-recompute + tile-partial softmin.
// 128x128 tile per block (4 waves). A/B fp16 tiles (16 KB each) are staged
// into LDS via global_load_lds width=16 with XOR-swizzled SOURCE addresses
// (rule: linear LDS dest + inverse-swz source + same swz on ds_read), then
// fragments come from ds_read_b128 — no per-lane scattered global loads and
// no 4x cross-wave B duplication.
// base_ij = min(dot - xn - yn, 0) * (log2e/eps)  (= -C_ij/eps in log2 units)
// then the verified two-phase (max, sum-of-exp2) reduction.
// ---------------------------------------------------------------------------
struct FusedArgs {
  const half_t* Af;     // fragment rows (x or y)
  const half_t* Bf;     // fragment cols
  const float* nrow;    // xn or yn for rows
  const float* ncol;    // for cols
  const float* hrow;    // h over cols (row direction softmin), log2 dom.
  const float* hcol;    // h over rows
  float2* prow;         // [b][chunk][row]
  float2* pcol;
  int sym;              // 1 => diagonal col-dir partial is skipped
};

union SharedU {
  half_t stage[2][TS * DD];                 // 2 x 16 KB (A | B)
  struct {
    float redR[TS][17], redC[TS][17];       // odd stride: reduce reads CF
    float rowM[TS], colM[TS];
  } r;
};

__global__ __launch_bounds__(256) void tile_fused(
    FusedArgs T0, FusedArgs T1, FusedArgs T2, float keps)   // keps = log2e/eps
{
  // flattened grid: 2048 xy tiles + 2*1088 triangular tiles = 4224 blocks
  int u = blockIdx.x;
  int slab, b, I, J;
  if (u < 2048) {
    slab = 0; b = u >> 8;
    int tt = u & 255; I = tt >> 4; J = tt & 15;
  } else {
    int v = u - 2048;
    slab = 1 + v / 1088;
    int w2 = v % 1088;
    b = w2 / 136;
    int rem = w2 % 136, ii = 0;
    while (rem >= NCHK - ii) { rem -= NCHK - ii; ++ii; }   // uniform, <=16 iters
    I = ii; J = ii + rem;                                  // I <= J
  }
  FusedArgs A = (slab == 0) ? T0 : (slab == 1) ? T1 : T2;

  const int t = threadIdx.x;
  const int w = t >> 6, lane = t & 63;
  const int m = lane & 15, quad = lane >> 4;
  const int i0 = I * TS, j0 = J * TS;

  __shared__ SharedU sh;
  char* lb = (char*)&sh;

  // ---- stage A (16 KB) + B (16 KB) into LDS via global_load_lds ----
  // 32 segments of 1 KB; wave w stages segments 8w..8w+7.
  // Linear LDS layout [row][128B]; source column XOR-swizzled by (row&7)<<4.
  {
    const char* gA = (const char*)(A.Af + ((size_t)b * NN + i0) * DD);
    const char* gB = (const char*)(A.Bf + ((size_t)b * MM + j0) * DD);
#pragma unroll
    for (int k = 0; k < 8; ++k) {
      int seg = w * 8 + k;                       // wave-uniform
      int p = (seg * 1024 + lane * 16) & 16383;  // byte pos within buffer
      int row = p >> 7, colb = p & 127;
      int colx = colb ^ ((row & 7) << 4);
      const char* src = (seg < 16 ? gA : gB) + (size_t)row * 128 + colx;
      __builtin_amdgcn_global_load_lds(
          (const __attribute__((address_space(1))) unsigned int*)src,
          (__attribute__((address_space(3))) unsigned int*)(lb + seg * 1024),
          16, 0, 0);
    }
  }

  // ---- per-thread row/col scalars (overlap with staging DMA) ----
  float4 xr[2], hq[2];
#pragma unroll
  for (int g = 0; g < 2; ++g) {
    size_t ro = (size_t)b * NN + i0 + 32 * w + 16 * g + 4 * quad;
    xr[g] = *(const float4*)(A.nrow + ro);
    hq[g] = *(const float4*)(A.hcol + ro);
  }
  float ynk[8], hr[8];
#pragma unroll
  for (int c = 0; c < 8; ++c) {
    size_t co = (size_t)b * MM + j0 + 16 * c + m;
    ynk[c] = -A.ncol[co] * keps;
    hr[c] = A.hrow[co];
  }
  float xnk[2][4], hcv[2][4];
#pragma unroll
  for (int g = 0; g < 2; ++g) {
    xnk[g][0] = -xr[g].x * keps; xnk[g][1] = -xr[g].y * keps;
    xnk[g][2] = -xr[g].z * keps; xnk[g][3] = -xr[g].w * keps;
    hcv[g][0] = hq[g].x; hcv[g][1] = hq[g].y;
    hcv[g][2] = hq[g].z; hcv[g][3] = hq[g].w;
  }

  __syncthreads();   // staging complete (drains vmcnt for global_load_lds)

  // ---- MFMA from LDS: dot products for this 128x128 tile ----
  // A frag row = 32w + 16g + m; B frag row = 16c + m; cols quad*16 + s*64 B.
  f32x4 acc[2][8];
#pragma unroll
  for (int g = 0; g < 2; ++g)
#pragma unroll
    for (int c = 0; c < 8; ++c) acc[g][c] = (f32x4){0.f, 0.f, 0.f, 0.f};

#pragma unroll
  for (int s = 0; s < 2; ++s) {
    int qb = quad * 16 + s * 64;
    int ra0 = 32 * w + m, ra1 = 32 * w + 16 + m;
    f16x8 a0 = *(const f16x8*)(lb + ra0 * 128 + (qb ^ ((ra0 & 7) << 4)));
    f16x8 a1 = *(const f16x8*)(lb + ra1 * 128 + (qb ^ ((ra1 & 7) << 4)));
#pragma unroll
    for (int c = 0; c < 8; ++c) {
      int rb = 16 * c + m;
      f16x8 bf = *(const f16x8*)(lb + 16384 + rb * 128 + (qb ^ ((rb & 7) << 4)));
      acc[0][c] = __builtin_amdgcn_mfma_f32_16x16x32_f16(a0, bf, acc[0][c], 0, 0, 0);
      acc[1][c] = __builtin_amdgcn_mfma_f32_16x16x32_f16(a1, bf, acc[1][c], 0, 0, 0);
    }
  }

  // ---- phase A: base conversion (in place, registers) + row/col maxes ----
  float rm[2][4], cm[8];
#pragma unroll
  for (int g = 0; g < 2; ++g)
#pragma unroll
    for (int r = 0; r < 4; ++r) rm[g][r] = -3.0e38f;
#pragma unroll
  for (int c = 0; c < 8; ++c) cm[c] = -3.0e38f;

#pragma unroll
  for (int g = 0; g < 2; ++g)
#pragma unroll
    for (int c = 0; c < 8; ++c) {
      f32x4 v = acc[g][c];
#pragma unroll
      for (int r = 0; r < 4; ++r) {
        float bse = fminf(fmaf(v[r], keps, xnk[g][r]) + ynk[c], 0.f);
        v[r] = bse;
        rm[g][r] = fmaxf(rm[g][r], bse + hr[c]);
        cm[c] = fmaxf(cm[c], bse + hcv[g][r]);
      }
      acc[g][c] = v;
    }

  __syncthreads();   // all waves done reading stage -> safe to reuse as red

#pragma unroll
  for (int g = 0; g < 2; ++g)
#pragma unroll
    for (int r = 0; r < 4; ++r)
      sh.r.redR[32 * w + 16 * g + 4 * quad + r][m] = rm[g][r];
#pragma unroll
  for (int c = 0; c < 8; ++c)
    sh.r.redC[16 * c + m][4 * w + quad] = cm[c];
  __syncthreads();
  if (t < TS) {
    float mx = sh.r.redR[t][0];
#pragma unroll
    for (int k = 1; k < 16; ++k) mx = fmaxf(mx, sh.r.redR[t][k]);
    sh.r.rowM[t] = mx;
  } else {
    int tt = t - TS;
    float mx = sh.r.redC[tt][0];
#pragma unroll
    for (int k = 1; k < 16; ++k) mx = fmaxf(mx, sh.r.redC[tt][k]);
    sh.r.colM[tt] = mx;
  }
  __syncthreads();

  float rmv[2][4], cmv[8];
#pragma unroll
  for (int g = 0; g < 2; ++g) {
    float4 q = *(const float4*)&sh.r.rowM[32 * w + 16 * g + 4 * quad];
    rmv[g][0] = q.x; rmv[g][1] = q.y; rmv[g][2] = q.z; rmv[g][3] = q.w;
  }
#pragma unroll
  for (int c = 0; c < 8; ++c) cmv[c] = sh.r.colM[16 * c + m];

  // ---- phase B: sums of exp2 (base values still in registers) ----
  float rs[2][4], cs[8];
#pragma unroll
  for (int g = 0; g < 2; ++g)
#pragma unroll
    for (int r = 0; r < 4; ++r) rs[g][r] = 0.f;
#pragma unroll
  for (int c = 0; c < 8; ++c) cs[c] = 0.f;

#pragma unroll
  for (int g = 0; g < 2; ++g)
#pragma unroll
    for (int c = 0; c < 8; ++c) {
      f32x4 v = acc[g][c];
#pragma unroll
      for (int r = 0; r < 4; ++r) {
        rs[g][r] += __builtin_amdgcn_exp2f(v[r] + hr[c] - rmv[g][r]);
        cs[c] += __builtin_amdgcn_exp2f(v[r] + hcv[g][r] - cmv[c]);
      }
    }

#pragma unroll
  for (int g = 0; g < 2; ++g)
#pragma unroll
    for (int r = 0; r < 4; ++r)
      sh.r.redR[32 * w + 16 * g + 4 * quad + r][m] = rs[g][r];
#pragma unroll
  for (int c = 0; c < 8; ++c)
    sh.r.redC[16 * c + m][4 * w + quad] = cs[c];
  __syncthreads();
  if (t < TS) {
    float s = 0.f;
#pragma unroll
    for (int k = 0; k < 16; ++k) s += sh.r.redR[t][k];
    A.prow[((size_t)b * NCHK + J) * NN + i0 + t] = make_float2(sh.r.rowM[t], s);
  } else {
    int tt = t - TS;
    if (!(A.sym && I == J)) {   // diagonal col-dir duplicates row-dir: skip
      float s = 0.f;
#pragma unroll
      for (int k = 0; k < 16; ++k) s += sh.r.redC[tt][k];
      A.pcol[((size_t)b * NCHK + I) * NN + j0 + tt] = make_float2(sh.r.colM[tt], s);
    }
  }
}

// ---------------------------------------------------------------------------
// merge 16 chunk-partials per row -> softmin + Jacobi update + next-h write.
// Partials in log2 domain: ft = -eps*ln2*(M + log2(S)).
// ---------------------------------------------------------------------------
struct MergeArgs {
  const float2* part;
  const float* fold;
  float* fout;
  const float* hbase;   // alog or blog (log2 domain)
  float* hout;          // h vector consumed by the next tile_fused
};

__global__ __launch_bounds__(256) void merge4(
    MergeArgs M0, MergeArgs M1, MergeArgs M2, MergeArgs M3,
    float eps, float alpha, float beta, float nextgs)
{
  MergeArgs A = (blockIdx.z == 0) ? M0 : (blockIdx.z == 1) ? M1
              : (blockIdx.z == 2) ? M2 : M3;
  const int b = blockIdx.y;
  const int i = blockIdx.x * 256 + threadIdx.x;   // grid.x = NN/256
  float2 p[NCHK];
#pragma unroll
  for (int k = 0; k < NCHK; ++k)
    p[k] = A.part[((size_t)b * NCHK + k) * NN + i];
  float M = p[0].x;
#pragma unroll
  for (int k = 1; k < NCHK; ++k) M = fmaxf(M, p[k].x);
  float S = 0.f;
#pragma unroll
  for (int k = 0; k < NCHK; ++k) S += p[k].y * __builtin_amdgcn_exp2f(p[k].x - M);
  float ft = (-LN2 * eps) * (M + __log2f(S));
  int idx = b * NN + i;
  float fnew = alpha * A.fold[idx] + beta * ft;
  A.fout[idx] = fnew;
  A.hout[idx] = fmaf(nextgs * L2E, fnew, A.hbase[idx]);
}

// ---------------------------------------------------------------------------
// loss = mean_b [ sum_i w1*(fabf - faaf) + sum_j w2*(gbaf - gbbf) ]
// ---------------------------------------------------------------------------
__global__ __launch_bounds__(256) void loss_kernel(
    const float* __restrict__ w1, const float* __restrict__ w2,
    float* __restrict__ out)
{
  __shared__ float red[256];
  float acc = 0.f;
  for (int idx = threadIdx.x; idx < NB * NN; idx += 256) {
    acc += w1[idx] * (g_fab[2][idx] - g_faa[2][idx])
         + w2[idx] * (g_gba[2][idx] - g_gbb[2][idx]);
  }
  red[threadIdx.x] = acc;
  __syncthreads();
  for (int s = 128; s > 0; s >>= 1) {
    if (threadIdx.x < s) red[threadIdx.x] += red[threadIdx.x + s];
    __syncthreads();
  }
  if (threadIdx.x == 0) out[0] = red[0] * (1.0f / NB);
}

// ---------------------------------------------------------------------------
extern "C" void kernel_launch(void* const* d_in, const int* in_sizes, int n_in,
                              void* d_out, int out_size, void* d_ws, size_t ws_size,
                              hipStream_t stream)
{
  const float* x = (const float*)d_in[0];
  const float* y = (const float*)d_in[1];
  const float* w1 = (const float*)d_in[2];
  const float* w2 = (const float*)d_in[3];
  float* out = (float*)d_out;

  half_t *xh, *yh;
  float *xn, *yn;
  float *h0, *h1, *h2, *h3, *fabp, *gbap, *faap, *gbbp, *alog, *blog;
  float2 *pfab, *pgba, *pfaa, *pgbb;
  hipGetSymbolAddress((void**)&xh, HIP_SYMBOL(g_xh));
  hipGetSymbolAddress((void**)&yh, HIP_SYMBOL(g_yh));
  hipGetSymbolAddress((void**)&xn, HIP_SYMBOL(g_xn));
  hipGetSymbolAddress((void**)&yn, HIP_SYMBOL(g_yn));
  hipGetSymbolAddress((void**)&h0, HIP_SYMBOL(g_h0));
  hipGetSymbolAddress((void**)&h1, HIP_SYMBOL(g_h1));
  hipGetSymbolAddress((void**)&h2, HIP_SYMBOL(g_h2));
  hipGetSymbolAddress((void**)&h3, HIP_SYMBOL(g_h3));
  hipGetSymbolAddress((void**)&fabp, HIP_SYMBOL(g_fab));
  hipGetSymbolAddress((void**)&gbap, HIP_SYMBOL(g_gba));
  hipGetSymbolAddress((void**)&faap, HIP_SYMBOL(g_faa));
  hipGetSymbolAddress((void**)&gbbp, HIP_SYMBOL(g_gbb));
  hipGetSymbolAddress((void**)&alog, HIP_SYMBOL(g_alog));
  hipGetSymbolAddress((void**)&blog, HIP_SYMBOL(g_blog));
  hipGetSymbolAddress((void**)&pfab, HIP_SYMBOL(g_pfab));
  hipGetSymbolAddress((void**)&pgba, HIP_SYMBOL(g_pgba));
  hipGetSymbolAddress((void**)&pfaa, HIP_SYMBOL(g_pfaa));
  hipGetSymbolAddress((void**)&pgbb, HIP_SYMBOL(g_pgbb));

  auto fab = [&](int s) { return fabp + (size_t)s * NB * NN; };
  auto gba = [&](int s) { return gbap + (size_t)s * NB * NN; };
  auto faa = [&](int s) { return faap + (size_t)s * NB * NN; };
  auto gbb = [&](int s) { return gbbp + (size_t)s * NB * NN; };

  // eps schedule (matches the Python double loop, then cast to fp32)
  float eps_list[32];
  int ne = 0;
  {
    double v = 64.0 * 64.0;
    double tgt = 0.05 * 0.05;
    while (v > tgt) { eps_list[ne++] = (float)v; v *= 0.25; }
    eps_list[ne++] = (float)tgt;   // ne == 12
  }

  prep_kernel<<<4096, 256, 0, stream>>>(x, y, w1, w2);

  dim3 tg(4224);                // flattened: 2048 xy + 1088 xx + 1088 yy
  dim3 mg(NN / 256, NB, 4);     // z: potential

  // one iteration: tile_fused (h already in place) + merge4 (writes next h)
  auto launch_iter = [&](float eps, float alpha, float beta, float nextgs,
                         int in, int outsel) {
    float keps = L2E / eps;
    FusedArgs T0 = {xh, yh, xn, yn, h0, h1, pfab, pgba, 0};
    FusedArgs T1 = {xh, xh, xn, xn, h2, h2, pfaa, pfaa, 1};
    FusedArgs T2 = {yh, yh, yn, yn, h3, h3, pgbb, pgbb, 1};
    tile_fused<<<tg, 256, 0, stream>>>(T0, T1, T2, keps);
    MergeArgs M0 = {pfab, fab(in), fab(outsel), alog, h1};
    MergeArgs M1 = {pgba, gba(in), gba(outsel), blog, h0};
    MergeArgs M2 = {pfaa, faa(in), faa(outsel), alog, h2};
    MergeArgs M3 = {pgbb, gbb(in), gbb(outsel), blog, h3};
    merge4<<<mg, 256, 0, stream>>>(M0, M1, M2, M3, eps, alpha, beta, nextgs);
  };

  // init at eps0: h = base log2-weights (gs=0), alpha=0 -> no carry read;
  // its merge writes h for scan step k=0.
  hprep_kernel<<<64, 256, 0, stream>>>(fab(0), gba(0), faa(0), gbb(0), 0.f);
  launch_iter(eps_list[0], 0.f, 1.f, 1.0f / eps_list[0], 0, 0);

  // scan over the full eps list with 0.5-averaging (Jacobi, banks 0/1);
  // each merge writes h for the NEXT step (k+1, or the final extrapolation).
  int cur = 0;
  for (int k = 0; k < ne; ++k) {
    int nxt = 1 - cur;
    float nextgs = 1.0f / ((k < ne - 1) ? eps_list[k + 1] : eps_list[ne - 1]);
    launch_iter(eps_list[k], 0.5f, 0.5f, nextgs, cur, nxt);
    cur = nxt;
  }

  // final extrapolation at eps = blur^p (no averaging) -> bank 2
  launch_iter(eps_list[ne - 1], 0.f, 1.f, 0.f, cur, 2);

  loss_kernel<<<1, 256, 0, stream>>>(w1, w2, out);
}